// Round 14
// baseline (137.309 us; speedup 1.0000x reference)
//
#include <hip/hip_runtime.h>
#include <stdint.h>

// Problem constants: n_class=32, n_support=16, n_query=16, D=1024;
// query rows Q = 512. Output (512, 32, 1024) fp32.
constexpr int NC = 32, NS = 16, NQ = 512, D = 1024;

// clang ext-vectors -> VOP3P packed fp32 (v_pk_fma_f32 etc., full-rate 2xf32)
typedef float v2f __attribute__((ext_vector_type(2)));
typedef float v4f __attribute__((ext_vector_type(4)));

// Packed quad accumulate (round-7 proven): acc += f(t0)+f(t1)+f(t2)+f(t3),
// f(t)=1/(exp2(t)+1), 2 rcp per 4 elements, packed full-rate ops.
// No clamp (validated rounds 3..13).
__device__ __forceinline__ void quad_acc(v2f t01, v2f t23, float& acc) {
    v2f A, B;
    A.x = __builtin_amdgcn_exp2f(t01.x);
    A.y = __builtin_amdgcn_exp2f(t01.y);
    B.x = __builtin_amdgcn_exp2f(t23.x);
    B.y = __builtin_amdgcn_exp2f(t23.y);
    A += 1.f;                  // v_pk_add
    B += 1.f;
    v2f prod = A * B;          // v_pk_mul
    v2f sum  = A + B;          // v_pk_add
    acc = fmaf(sum.x, __builtin_amdgcn_rcpf(prod.x), acc);
    acc = fmaf(sum.y, __builtin_amdgcn_rcpf(prod.y), acc);
}

// Direct global->LDS DMA, 16B/lane, zero VGPR round-trip (round-8 proven).
__device__ __forceinline__ void gload_lds16(const float* g, float* l) {
    __builtin_amdgcn_global_load_lds(
        (const __attribute__((address_space(1))) void*)g,
        (__attribute__((address_space(3))) void*)l,
        16, 0, 0);
}

// ================== Kernel A: scores + softmax -> att ==================
// QPB=16 (4 queries/wave): sc[4][16]=64 regs is affordable WITHOUT the proto
// tail (R12's spill came from sc64 + proto accs together). 32KB quarter
// double-buffer, DMA-rotated, 4 barriers. grid=1024 -> 4 blocks/CU, one
// resident generation, 4 waves/SIMD feeding the trans pipe (the measured
// bottleneck: T ~ 13cy/wave trans op -> ~34us of trans work chip-wide).
// att[q,c,0:16] is written into out[q,c,0:16] (scratch; kernel B consumes
// then overwrites). Tripwire: WRITE_SIZE ~ 1024 KB, no more.
__global__ __launch_bounds__(256, 2)
void score_kernel(const float* __restrict__ data, float* __restrict__ out) {
    const int c    = blockIdx.x;
    const int qt   = blockIdx.y;   // tile of 16 queries
    const int tid  = threadIdx.x;
    const int wave = tid >> 6;
    const int lane = tid & 63;

    __shared__ __align__(16) float buf[2][NS * 256];   // 2 x 16KB quarters
    const float* sup = data + (size_t)c * NS * D;

    auto stage = [&](int p, int b) {
        #pragma unroll
        for (int r = 0; r < 4; ++r) {
            int row = 4 * wave + r;
            gload_lds16(sup + row * D + p * 256 + lane * 4, &buf[b][row * 256]);
        }
    };

    const float K = 2.88539008177792681472f;   // 2*log2(e)
    const int q0 = qt * 16 + wave * 4;
    const v4f* qg = reinterpret_cast<const v4f*>(data + (size_t)(NC * NS + q0) * D);

    stage(0, 0);
    __syncthreads();

    float sc[4][NS];
    #pragma unroll
    for (int r = 0; r < 4; ++r)
        #pragma unroll
        for (int s = 0; s < NS; ++s) sc[r][s] = 0.f;

    #pragma unroll
    for (int p = 0; p < 4; ++p) {
        if (p < 3) stage(p + 1, (p + 1) & 1);
        v4f q[4];
        #pragma unroll
        for (int r = 0; r < 4; ++r) q[r] = qg[r * 256 + (p << 6) + lane] * K;
        const v4f* B = reinterpret_cast<const v4f*>(buf[p & 1]);
        #pragma unroll
        for (int s = 0; s < NS; ++s) {
            v4f sv = B[(s << 6) + lane];
            #pragma unroll
            for (int r = 0; r < 4; ++r)
                quad_acc(sv.xy * q[r].xy, sv.zw * q[r].zw, sc[r][s]);
        }
        if (p < 3) __syncthreads();
    }

    // wave64 butterfly reduction + softmax per query (replicated per lane)
    const float L2E = 1.44269504088896340736f;
    #pragma unroll
    for (int r = 0; r < 4; ++r) {
        #pragma unroll
        for (int s = 0; s < NS; ++s) {
            float v = sc[r][s];
            #pragma unroll
            for (int m = 32; m >= 1; m >>= 1) v += __shfl_xor(v, m, 64);
            sc[r][s] = (float)D - 2.f * v;
        }
        float mx = sc[r][0];
        #pragma unroll
        for (int s = 1; s < NS; ++s) mx = fmaxf(mx, sc[r][s]);
        float sum = 0.f;
        #pragma unroll
        for (int s = 0; s < NS; ++s) {
            sc[r][s] = __builtin_amdgcn_exp2f((sc[r][s] - mx) * L2E);
            sum += sc[r][s];
        }
        const float inv = __builtin_amdgcn_rcpf(sum);
        #pragma unroll
        for (int s = 0; s < NS; ++s) sc[r][s] *= inv;
    }

    // write att[q,c,s] into out[q,c,0:16]: lane s takes value s via cndmask
    #pragma unroll
    for (int r = 0; r < 4; ++r) {
        float v = 0.f;
        #pragma unroll
        for (int s = 0; s < NS; ++s) v = (lane == s) ? sc[r][s] : v;
        if (lane < NS)
            out[((size_t)(q0 + r) * NC + c) * D + lane] = v;
    }
}

// ================== Kernel B: proto from att ==================
// QPB=8 (2 q/wave). att loaded first (wave-uniform addresses -> scalar
// loads), then 32KB DMA-rotated quarters, proto packed FMAs, per-phase
// stores (overwriting the att scratch AFTER it is register-held).
// ~60 VGPR -> high occupancy; HBM-write-bound (~64MB -> ~12us floor).
__global__ __launch_bounds__(256, 2)
void proto_kernel(const float* __restrict__ data, float* __restrict__ out) {
    const int c    = blockIdx.x;
    const int qt   = blockIdx.y;   // tile of 8 queries
    const int tid  = threadIdx.x;
    const int wave = tid >> 6;
    const int lane = tid & 63;

    __shared__ __align__(16) float buf[2][NS * 256];   // 2 x 16KB quarters
    const float* sup = data + (size_t)c * NS * D;

    auto stage = [&](int p, int b) {
        #pragma unroll
        for (int r = 0; r < 4; ++r) {
            int row = 4 * wave + r;
            gload_lds16(sup + row * D + p * 256 + lane * 4, &buf[b][row * 256]);
        }
    };

    const int q0 = qt * 8 + wave * 2;
    float* orow0 = out + ((size_t)q0 * NC + c) * D;
    float* orow1 = orow0 + (size_t)NC * D;

    stage(0, 0);   // DMA under the att loads below

    // att for this wave's 2 queries (written by score_kernel into out[..,0:16])
    float a0[NS], a1[NS];
    #pragma unroll
    for (int s = 0; s < NS; ++s) { a0[s] = orow0[s]; a1[s] = orow1[s]; }
    __syncthreads();   // vmcnt drain -> quarter 0 staged

    v4f* og0 = reinterpret_cast<v4f*>(orow0);
    v4f* og1 = reinterpret_cast<v4f*>(orow1);

    #pragma unroll
    for (int p = 0; p < 4; ++p) {
        if (p < 3) stage(p + 1, (p + 1) & 1);
        const v4f* B = reinterpret_cast<const v4f*>(buf[p & 1]);
        v2f oxy0 = 0.f, ozw0 = 0.f, oxy1 = 0.f, ozw1 = 0.f;
        #pragma unroll
        for (int s = 0; s < NS; ++s) {
            v4f sv = B[(s << 6) + lane];
            oxy0 += sv.xy * a0[s];   // v_pk_fma_f32
            ozw0 += sv.zw * a0[s];
            oxy1 += sv.xy * a1[s];
            ozw1 += sv.zw * a1[s];
        }
        v4f r0, r1;
        r0.xy = oxy0; r0.zw = ozw0;
        r1.xy = oxy1; r1.zw = ozw1;
        og0[(p << 6) + lane] = r0;
        og1[(p << 6) + lane] = r1;
        if (p < 3) __syncthreads();
    }
}

extern "C" void kernel_launch(void* const* d_in, const int* in_sizes, int n_in,
                              void* d_out, int out_size, void* d_ws, size_t ws_size,
                              hipStream_t stream) {
    (void)in_sizes; (void)n_in; (void)out_size; (void)d_ws; (void)ws_size;
    const float* data = (const float*)d_in[0];
    float* out = (float*)d_out;
    // A: 32 classes x 32 tiles(16q) = 1024 blocks = one resident generation.
    score_kernel<<<dim3(NC, NQ / 16), dim3(256), 0, stream>>>(data, out);
    // B: 32 classes x 64 tiles(8q) = 2048 blocks; stream-ordered after A.
    proto_kernel<<<dim3(NC, NQ / 8), dim3(256), 0, stream>>>(data, out);
}